// Round 8
// baseline (155.670 us; speedup 1.0000x reference)
//
#include <hip/hip_runtime.h>
#include <stdint.h>

#define BATCH   2048
#define KDIM    4096
#define NDIM    11008

#define BM 128
#define BN 256
#define BK 64
#define NT (KDIM / BK)               // 64 K-tiles
#define ABYTES (BM * BK)             // 8192
#define BBYTES (BN * BK)             // 16384
#define BUF_BYTES (ABYTES + BBYTES)  // 24576
#define A_OFF 0
#define B_OFF ABYTES

typedef __attribute__((ext_vector_type(4))) int i32x4;

typedef const __attribute__((address_space(1))) char glob_char;
typedef __attribute__((address_space(3))) char lds_char;

__device__ __forceinline__ unsigned pack4(i32x4 v) {
  return  ((unsigned)v.x & 0xFFu)
        | (((unsigned)v.y & 0xFFu) << 8)
        | (((unsigned)v.z & 0xFFu) << 16)
        | (((unsigned)v.w)         << 24);
}

__global__ __launch_bounds__(256) void convert_i32_i8(const int* __restrict__ src,
                                                      unsigned* __restrict__ dst,
                                                      int n4) {
  int idx = blockIdx.x * 256 + threadIdx.x;
  if (idx >= n4) return;
  i32x4 v = ((const i32x4*)src)[idx];
  dst[idx] = pack4(v);
}

// C[2048][11008] = A[2048][4096] * W[11008][4096]^T via mfma_i32_16x16x64_i8.
// R8 = R7 sync skeleton x R5 geometry x L2-aware rasterization:
//  - 128x256 tile (1.05 GB total staging traffic vs 128x128's 1.39 GB),
//    4 waves (2m x 2n), per-wave 64x128 = 4x8 frags, 32 MFMA + 12 ds_read
//    per wave-KT (best MFMA:LDS ratio at acc=128 AGPR).
//  - 3 rotating 24KB buffers (72 KB LDS, 2 blocks/CU), depth-2 prefetch,
//    ONE counted vmcnt(6) + ONE s_barrier per KT64; reads hit cur while
//    stages hit pf (disjoint) -> no inner barriers. After barrier(t-1) all
//    t-1 ds_reads have retired (their MFMA consumers ran) so iter-t writes
//    into that buffer are race-free (R7-validated pattern).
//  - NO manual lgkmcnt / sched_barrier (R6 regression lesson).
//  - Rasterization: mtl fastest within 4-wide mt-supertile -> each XCD's
//    172-wg chunk = 4 A-panels (2 MB) x 43 nt, so A re-reads are L2-hits
//    (A-LLC traffic 344 MB -> ~16 MB); consecutive 4 wg share the B-panel.
// Slot swizzle (validated, 0 conflicts): 64B rows, physical 16B slot
// p = logical ^ ((row>>1)&3); applied on the global SOURCE for
// global_load_lds (linear dest) and on the ds_read address.
__global__ __launch_bounds__(256, 2) void ternary_gemm(const char* __restrict__ A8,
                                                       const char* __restrict__ B8,
                                                       const float* __restrict__ scale,
                                                       const float* __restrict__ bias,
                                                       float* __restrict__ out) {
  __shared__ char lds[3 * BUF_BYTES];   // 73728 B -> 2 blocks/CU

  const int tid  = threadIdx.x;
  const int wid  = tid >> 6;
  const int lane = tid & 63;

  // XCD swizzle (688 % 8 == 0 -> bijective) + 4-wide mt-supertile raster
  const int wg  = (blockIdx.x & 7) * 86 + (blockIdx.x >> 3);
  const int mtq = wg / 172;             // 0..3 : which group of 4 M-tiles
  const int r   = wg - mtq * 172;       // 0..171
  const int nt  = r >> 2;               // 0..42
  const int mt  = mtq * 4 + (r & 3);    // 0..15, mtl fastest
  const int arow0 = mt * BM;
  const int brow0 = nt * BN;

  const int wr = wid >> 1;              // 0..1 : 64-row half
  const int wc = wid & 1;               // 0..1 : 128-col half
  const int rsub = lane & 15;
  const int sgrp = lane >> 4;           // k-slot 0..3 (16 i8 each)

  // staging: 256 thr x 16B = 4KB/round = 64 rows; A rounds 0-1, B rounds 0-3
  const int srow  = tid >> 2;           // 0..63
  const int sslot = (tid & 3) ^ ((srow >> 1) & 3);  // +r*64 preserves row bits 1-2
  const char* gA0 = A8 + (size_t)(arow0       + srow) * KDIM + sslot * 16;
  const char* gA1 = A8 + (size_t)(arow0 +  64 + srow) * KDIM + sslot * 16;
  const char* gB0 = B8 + (size_t)(brow0       + srow) * KDIM + sslot * 16;
  const char* gB1 = B8 + (size_t)(brow0 +  64 + srow) * KDIM + sslot * 16;
  const char* gB2 = B8 + (size_t)(brow0 + 128 + srow) * KDIM + sslot * 16;
  const char* gB3 = B8 + (size_t)(brow0 + 192 + srow) * KDIM + sslot * 16;

  auto stage = [&](const char* g, int bufo, int kt, int dsto) {
    __builtin_amdgcn_global_load_lds((glob_char*)(g + kt * BK),
        (lds_char*)(lds + bufo + dsto + wid * 1024), 16, 0, 0);
  };
  auto stage_tile = [&](int bufo, int kt) {
    stage(gA0, bufo, kt, A_OFF);
    stage(gA1, bufo, kt, A_OFF + 4096);
    stage(gB0, bufo, kt, B_OFF);
    stage(gB1, bufo, kt, B_OFF + 4096);
    stage(gB2, bufo, kt, B_OFF + 8192);
    stage(gB3, bufo, kt, B_OFF + 12288);
  };

  // loop-invariant fragment byte-offsets (0-conflict pattern)
  int offA[4], offB[8];
#pragma unroll
  for (int m = 0; m < 4; ++m) {
    const int row = wr * 64 + m * 16 + rsub;
    const int p   = sgrp ^ ((row >> 1) & 3);
    offA[m] = A_OFF + row * 64 + p * 16;
  }
#pragma unroll
  for (int n = 0; n < 8; ++n) {
    const int row = wc * 128 + n * 16 + rsub;
    const int p   = sgrp ^ ((row >> 1) & 3);
    offB[n] = B_OFF + row * 64 + p * 16;
  }

  i32x4 acc[4][8];
#pragma unroll
  for (int m = 0; m < 4; ++m)
#pragma unroll
    for (int n = 0; n < 8; ++n)
      acc[m][n] = (i32x4){0, 0, 0, 0};

  int cur = 0, nxt = BUF_BYTES, pf = 2 * BUF_BYTES;

  // prologue: stage tiles 0 and 1; wait tile 0 (oldest 6) only
  stage_tile(cur, 0);
  stage_tile(nxt, 1);
  asm volatile("s_waitcnt vmcnt(6)" ::: "memory");
  __builtin_amdgcn_s_barrier();

  for (int t = 0; t < NT; ++t) {
    const int kt2 = (t + 2 < NT) ? t + 2 : NT - 1;   // clamped dummy at tail

    // stage tile t+2 into pf (== cur(t-1); safe after barrier(t-1))
    stage_tile(pf, kt2);

    // read this tile's 12 frags from cur
    i32x4 a0 = *(const i32x4*)(lds + cur + offA[0]);
    i32x4 a1 = *(const i32x4*)(lds + cur + offA[1]);
    i32x4 a2 = *(const i32x4*)(lds + cur + offA[2]);
    i32x4 a3 = *(const i32x4*)(lds + cur + offA[3]);
    i32x4 b0 = *(const i32x4*)(lds + cur + offB[0]);
    i32x4 b1 = *(const i32x4*)(lds + cur + offB[1]);
    i32x4 b2 = *(const i32x4*)(lds + cur + offB[2]);
    i32x4 b3 = *(const i32x4*)(lds + cur + offB[3]);
    i32x4 b4 = *(const i32x4*)(lds + cur + offB[4]);
    i32x4 b5 = *(const i32x4*)(lds + cur + offB[5]);
    i32x4 b6 = *(const i32x4*)(lds + cur + offB[6]);
    i32x4 b7 = *(const i32x4*)(lds + cur + offB[7]);

    __builtin_amdgcn_s_setprio(1);
    acc[0][0] = __builtin_amdgcn_mfma_i32_16x16x64_i8(a0, b0, acc[0][0], 0, 0, 0);
    acc[1][0] = __builtin_amdgcn_mfma_i32_16x16x64_i8(a1, b0, acc[1][0], 0, 0, 0);
    acc[2][0] = __builtin_amdgcn_mfma_i32_16x16x64_i8(a2, b0, acc[2][0], 0, 0, 0);
    acc[3][0] = __builtin_amdgcn_mfma_i32_16x16x64_i8(a3, b0, acc[3][0], 0, 0, 0);
    acc[0][1] = __builtin_amdgcn_mfma_i32_16x16x64_i8(a0, b1, acc[0][1], 0, 0, 0);
    acc[1][1] = __builtin_amdgcn_mfma_i32_16x16x64_i8(a1, b1, acc[1][1], 0, 0, 0);
    acc[2][1] = __builtin_amdgcn_mfma_i32_16x16x64_i8(a2, b1, acc[2][1], 0, 0, 0);
    acc[3][1] = __builtin_amdgcn_mfma_i32_16x16x64_i8(a3, b1, acc[3][1], 0, 0, 0);
    acc[0][2] = __builtin_amdgcn_mfma_i32_16x16x64_i8(a0, b2, acc[0][2], 0, 0, 0);
    acc[1][2] = __builtin_amdgcn_mfma_i32_16x16x64_i8(a1, b2, acc[1][2], 0, 0, 0);
    acc[2][2] = __builtin_amdgcn_mfma_i32_16x16x64_i8(a2, b2, acc[2][2], 0, 0, 0);
    acc[3][2] = __builtin_amdgcn_mfma_i32_16x16x64_i8(a3, b2, acc[3][2], 0, 0, 0);
    acc[0][3] = __builtin_amdgcn_mfma_i32_16x16x64_i8(a0, b3, acc[0][3], 0, 0, 0);
    acc[1][3] = __builtin_amdgcn_mfma_i32_16x16x64_i8(a1, b3, acc[1][3], 0, 0, 0);
    acc[2][3] = __builtin_amdgcn_mfma_i32_16x16x64_i8(a2, b3, acc[2][3], 0, 0, 0);
    acc[3][3] = __builtin_amdgcn_mfma_i32_16x16x64_i8(a3, b3, acc[3][3], 0, 0, 0);
    acc[0][4] = __builtin_amdgcn_mfma_i32_16x16x64_i8(a0, b4, acc[0][4], 0, 0, 0);
    acc[1][4] = __builtin_amdgcn_mfma_i32_16x16x64_i8(a1, b4, acc[1][4], 0, 0, 0);
    acc[2][4] = __builtin_amdgcn_mfma_i32_16x16x64_i8(a2, b4, acc[2][4], 0, 0, 0);
    acc[3][4] = __builtin_amdgcn_mfma_i32_16x16x64_i8(a3, b4, acc[3][4], 0, 0, 0);
    acc[0][5] = __builtin_amdgcn_mfma_i32_16x16x64_i8(a0, b5, acc[0][5], 0, 0, 0);
    acc[1][5] = __builtin_amdgcn_mfma_i32_16x16x64_i8(a1, b5, acc[1][5], 0, 0, 0);
    acc[2][5] = __builtin_amdgcn_mfma_i32_16x16x64_i8(a2, b5, acc[2][5], 0, 0, 0);
    acc[3][5] = __builtin_amdgcn_mfma_i32_16x16x64_i8(a3, b5, acc[3][5], 0, 0, 0);
    acc[0][6] = __builtin_amdgcn_mfma_i32_16x16x64_i8(a0, b6, acc[0][6], 0, 0, 0);
    acc[1][6] = __builtin_amdgcn_mfma_i32_16x16x64_i8(a1, b6, acc[1][6], 0, 0, 0);
    acc[2][6] = __builtin_amdgcn_mfma_i32_16x16x64_i8(a2, b6, acc[2][6], 0, 0, 0);
    acc[3][6] = __builtin_amdgcn_mfma_i32_16x16x64_i8(a3, b6, acc[3][6], 0, 0, 0);
    acc[0][7] = __builtin_amdgcn_mfma_i32_16x16x64_i8(a0, b7, acc[0][7], 0, 0, 0);
    acc[1][7] = __builtin_amdgcn_mfma_i32_16x16x64_i8(a1, b7, acc[1][7], 0, 0, 0);
    acc[2][7] = __builtin_amdgcn_mfma_i32_16x16x64_i8(a2, b7, acc[2][7], 0, 0, 0);
    acc[3][7] = __builtin_amdgcn_mfma_i32_16x16x64_i8(a3, b7, acc[3][7], 0, 0, 0);
    __builtin_amdgcn_s_setprio(0);

    // tile t+1's 6 loads retire (t+2's 6 stay in flight); publish block-wide
    asm volatile("s_waitcnt vmcnt(6)" ::: "memory");
    __builtin_amdgcn_s_barrier();

    const int tb = cur; cur = nxt; nxt = pf; pf = tb;
  }

  // Epilogue (validated R1-R7): C/D col = lane&15, row = (lane>>4)*4 + reg
  const int crow = sgrp * 4;
#pragma unroll
  for (int n = 0; n < 8; ++n) {
    const int col = brow0 + wc * 128 + n * 16 + rsub;
    const float sc = scale[col];
    const float bs = bias[col];
#pragma unroll
    for (int m = 0; m < 4; ++m) {
      const int r0 = arow0 + wr * 64 + m * 16 + crow;
#pragma unroll
      for (int j = 0; j < 4; ++j) {
        out[(size_t)(r0 + j) * NDIM + col] = (float)acc[m][n][j] * sc + bs;
      }
    }
  }
}

extern "C" void kernel_launch(void* const* d_in, const int* in_sizes, int n_in,
                              void* d_out, int out_size, void* d_ws, size_t ws_size,
                              hipStream_t stream) {
  const int*   input  = (const int*)d_in[0];     // [2048][4096] int32
  const int*   weight = (const int*)d_in[1];     // [11008][4096] int32 in {-1,0,1}
  const float* scale  = (const float*)d_in[2];   // [11008]
  const float* bias   = (const float*)d_in[3];   // [11008]
  float*       out    = (float*)d_out;           // [2048][11008] fp32

  const size_t needA = (size_t)BATCH * KDIM;     // 8 MB int8
  const size_t needB = (size_t)NDIM * KDIM;      // 44 MB int8

  char* A8 = (char*)d_ws;
  char* B8 = A8 + needA;
  const int nA4 = (int)(needA / 4);
  const int nB4 = (int)(needB / 4);
  convert_i32_i8<<<(nA4 + 255) / 256, 256, 0, stream>>>(input, (unsigned*)A8, nA4);
  convert_i32_i8<<<(nB4 + 255) / 256, 256, 0, stream>>>(weight, (unsigned*)B8, nB4);

  const dim3 grid((BATCH / BM) * (NDIM / BN));   // 16 * 43 = 688
  const dim3 block(256);
  ternary_gemm<<<grid, block, 0, stream>>>(A8, B8, scale, bias, out);
  (void)ws_size; (void)n_in; (void)in_sizes; (void)out_size;
}